// Round 3
// baseline (1629.973 us; speedup 1.0000x reference)
//
#include <hip/hip_runtime.h>

#define HW      4096      // 64*64 pixels
#define WIMG    64
#define CIN     256
#define C3      768
#define CCAT    512
#define COUT    256
#define BATCH   16
#define EPS_F   1e-5f

// ---------------------------------------------------------------------------
// K1: 1x1 conv as GEMM (f32): out[b,c,n] = relu(scale[c]*dot(w[c,:],in[b,:,n])+bias[c])
// 256 threads -> 64 ch x 64 px tile, K chunks of 16.
// ---------------------------------------------------------------------------
template <int K>
__global__ __launch_bounds__(256) void conv1x1_bn_relu(
    const float* __restrict__ in,     // (B, K, HW)
    const float* __restrict__ w,      // (Ctot, K)
    const float* __restrict__ scale,
    const float* __restrict__ bias,
    float* __restrict__ out,          // (B, Ctot, HW)
    int Ctot)
{
    const int pt  = blockIdx.x * 64;
    const int ct  = blockIdx.y * 64;
    const int b   = blockIdx.z;
    const int tid = threadIdx.x;
    const int tx  = tid & 15;
    const int ty  = tid >> 4;

    __shared__ float Ws[16][64];
    __shared__ float Xs[16][64];

    float acc[4][4] = {};
    const float* xb = in + (size_t)b * K * HW + pt;

    for (int k0 = 0; k0 < K; k0 += 16) {
        #pragma unroll
        for (int i = 0; i < 4; i++) {
            int idx = tid + i * 256;
            int c = idx >> 4, k = idx & 15;
            Ws[k][c] = w[(size_t)(ct + c) * K + k0 + k];
        }
        #pragma unroll
        for (int i = 0; i < 4; i++) {
            int idx = tid + i * 256;
            int k = idx >> 6, p = idx & 63;
            Xs[k][p] = xb[(size_t)(k0 + k) * HW + p];
        }
        __syncthreads();
        #pragma unroll
        for (int kk = 0; kk < 16; kk++) {
            float4 av = *reinterpret_cast<const float4*>(&Ws[kk][ty * 4]);
            float4 bv = *reinterpret_cast<const float4*>(&Xs[kk][tx * 4]);
            float a[4] = {av.x, av.y, av.z, av.w};
            float bb[4] = {bv.x, bv.y, bv.z, bv.w};
            #pragma unroll
            for (int i = 0; i < 4; i++)
                #pragma unroll
                for (int j = 0; j < 4; j++)
                    acc[i][j] += a[i] * bb[j];
        }
        __syncthreads();
    }

    #pragma unroll
    for (int i = 0; i < 4; i++) {
        int c = ct + ty * 4 + i;
        float s = scale[c];
        float bi = bias[c];
        float4 v;
        v.x = fmaxf(acc[i][0] * s + bi, 0.f);
        v.y = fmaxf(acc[i][1] * s + bi, 0.f);
        v.z = fmaxf(acc[i][2] * s + bi, 0.f);
        v.w = fmaxf(acc[i][3] * s + bi, 0.f);
        float* dst = out + ((size_t)b * Ctot + c) * HW + pt + tx * 4;
        *reinterpret_cast<float4*>(dst) = v;
    }
}

// ---------------------------------------------------------------------------
// K2: attention stats for heads 0..31 (direct from qkv, f32).
// vk[d][e] = sum_n v_d(n) k_e(n), ksum[e] = sum_n k_e(n); k relu'd.
// ---------------------------------------------------------------------------
__global__ __launch_bounds__(256) void attn_stats_direct(
    const float* __restrict__ qkv,
    float* __restrict__ stats)        // (B, 64, 72)
{
    const int h   = blockIdx.x;       // 0..31
    const int b   = blockIdx.y;
    const int tid = threadIdx.x;
    const int lane = tid & 63;
    const int wave = tid >> 6;

    const float* src = qkv + ((size_t)b * C3 + h * 24) * HW;

    float acc[72];
    #pragma unroll
    for (int i = 0; i < 72; i++) acc[i] = 0.f;

    for (int p = tid; p < HW; p += 256) {
        float kv[8], vv[8];
        #pragma unroll
        for (int e = 0; e < 8; e++) kv[e] = fmaxf(src[(size_t)(8 + e) * HW + p], 0.f);
        #pragma unroll
        for (int d = 0; d < 8; d++) vv[d] = src[(size_t)(16 + d) * HW + p];
        #pragma unroll
        for (int d = 0; d < 8; d++)
            #pragma unroll
            for (int e = 0; e < 8; e++)
                acc[d * 8 + e] += vv[d] * kv[e];
        #pragma unroll
        for (int e = 0; e < 8; e++) acc[64 + e] += kv[e];
    }

    __shared__ float red[4][72];
    #pragma unroll
    for (int i = 0; i < 72; i++) {
        float v = acc[i];
        v += __shfl_down(v, 32);
        v += __shfl_down(v, 16);
        v += __shfl_down(v, 8);
        v += __shfl_down(v, 4);
        v += __shfl_down(v, 2);
        v += __shfl_down(v, 1);
        if (lane == 0) red[wave][i] = v;
    }
    __syncthreads();
    if (tid < 72)
        stats[((size_t)b * 64 + h) * 72 + tid] =
            red[0][tid] + red[1][tid] + red[2][tid] + red[3][tid];
}

// ---------------------------------------------------------------------------
// K3: attention stats for heads 32..63: on-the-fly depthwise 5x5 + affine of
// qkv channels (k,v of head block), then vk/ksum accumulation. agg is never
// materialized. One block per (h', b); 8-row strips staged in LDS.
// ---------------------------------------------------------------------------
__global__ __launch_bounds__(256) void attn_stats_dw(
    const float* __restrict__ qkv,
    const float* __restrict__ dww,    // (C3, 25)
    const float* __restrict__ dwb,
    const float* __restrict__ pww,
    const float* __restrict__ pwb,
    float* __restrict__ stats)
{
    const int hp  = blockIdx.x;       // 0..31 -> global head 32+hp
    const int b   = blockIdx.y;
    const int tid = threadIdx.x;
    const int lane = tid & 63;
    const int wave = tid >> 6;
    const int base = hp * 24 + 8;     // first of 16 channels (8 k, then 8 v)

    __shared__ float stg[16][12][68]; // 52.2 KiB: rows ys-2..ys+9
    __shared__ float red[4][72];

    float acc[72];
    #pragma unroll
    for (int i = 0; i < 72; i++) acc[i] = 0.f;

    for (int ys = 0; ys < WIMG; ys += 8) {
        __syncthreads();
        for (int i = tid; i < 16 * 12 * 68; i += 256) {
            int ch  = i / (12 * 68);
            int rem = i - ch * (12 * 68);
            int r   = rem / 68;
            int col = rem - r * 68;
            int y = ys + r - 2;
            int x = col - 2;
            float v = 0.f;
            if (y >= 0 && y < WIMG && x >= 0 && x < WIMG)
                v = qkv[((size_t)b * C3 + base + ch) * HW + y * WIMG + x];
            stg[ch][r][col] = v;
        }
        __syncthreads();

        #pragma unroll
        for (int half = 0; half < 2; half++) {
            int idx = tid + half * 256;       // 0..511 -> 8 rows x 64 cols
            int r = idx >> 6;                 // 0..7 output row in strip
            int x = idx & 63;
            float kv[8], vv[8];
            #pragma unroll
            for (int j = 0; j < 16; j++) {
                int c = base + j;
                // block-uniform weight reads -> scalar loads
                const float* wr = &dww[c * 25];
                float s = 0.f;
                #pragma unroll
                for (int ky = 0; ky < 5; ky++)
                    #pragma unroll
                    for (int kx = 0; kx < 5; kx++)
                        s += wr[ky * 5 + kx] * stg[j][r + ky][x + kx];
                float pw = pww[c];
                float val = s * pw + (pw * dwb[c] + pwb[c]);
                if (j < 8) kv[j] = fmaxf(val, 0.f);
                else       vv[j - 8] = val;
            }
            #pragma unroll
            for (int d = 0; d < 8; d++)
                #pragma unroll
                for (int e = 0; e < 8; e++)
                    acc[d * 8 + e] += vv[d] * kv[e];
            #pragma unroll
            for (int e = 0; e < 8; e++) acc[64 + e] += kv[e];
        }
    }

    #pragma unroll
    for (int i = 0; i < 72; i++) {
        float v = acc[i];
        v += __shfl_down(v, 32);
        v += __shfl_down(v, 16);
        v += __shfl_down(v, 8);
        v += __shfl_down(v, 4);
        v += __shfl_down(v, 2);
        v += __shfl_down(v, 1);
        if (lane == 0) red[wave][i] = v;
    }
    __syncthreads();
    if (tid < 72)
        stats[((size_t)b * 64 + 32 + hp) * 72 + tid] =
            red[0][tid] + red[1][tid] + red[2][tid] + red[3][tid];
}

// ---------------------------------------------------------------------------
// K4: fused attention pass-2 + proj conv + BN + ReLU, all f32.
// Grid (64 rows, B); block computes all 256 out-channels x 64 px (one image
// row). Loops 64 heads: q (direct or on-the-fly dwconv) -> attn values (8 x
// 64 in LDS) -> rank-8 proj accumulation. Small LDS (~23 KiB).
// ---------------------------------------------------------------------------
__global__ __launch_bounds__(256) void attn_proj(
    const float* __restrict__ qkv,
    const float* __restrict__ dww,
    const float* __restrict__ dwb,
    const float* __restrict__ pww,
    const float* __restrict__ pwb,
    const float* __restrict__ stats,  // (B, 64, 72)
    const float* __restrict__ w,      // (COUT, CCAT)
    const float* __restrict__ scale,
    const float* __restrict__ bias,
    float* __restrict__ out)          // (B, COUT, HW)
{
    const int row = blockIdx.x;       // image row
    const int b   = blockIdx.y;
    const int pt  = row * 64;
    const int tid = threadIdx.x;
    const int tx  = tid & 15;         // 4 px each
    const int ty  = tid >> 4;         // 16 ch each

    __shared__ float qstage[8][5][68];   // 10.9 KiB
    __shared__ float qbuf[8][64];        // raw q (relu at use)
    __shared__ float abuf[8][64];        // attn values
    __shared__ float Wp[256][8];         // proj w slice [c][d]
    __shared__ float sstat[72];

    float acc[16][4] = {};

    for (int h = 0; h < 64; h++) {
        const int cbase = (h < 32) ? h * 24 : (h - 32) * 24;
        __syncthreads();   // protect LDS from previous iteration's readers

        if (tid < 72) sstat[tid] = stats[((size_t)b * 64 + h) * 72 + tid];
        {   // stage proj weight slice: Wp[c][d] = w[c, h*8+d]
            const float* wsrc = w + (size_t)tid * CCAT + h * 8;
            float4 w0 = *reinterpret_cast<const float4*>(wsrc);
            float4 w1 = *reinterpret_cast<const float4*>(wsrc + 4);
            *reinterpret_cast<float4*>(&Wp[tid][0]) = w0;
            *reinterpret_cast<float4*>(&Wp[tid][4]) = w1;
        }

        if (h < 32) {
            #pragma unroll
            for (int i = 0; i < 2; i++) {
                int idx = tid + i * 256;
                int e = idx >> 6, px = idx & 63;
                qbuf[e][px] = qkv[((size_t)b * C3 + cbase + e) * HW + pt + px];
            }
        } else {
            for (int i = tid; i < 8 * 5 * 68; i += 256) {
                int ch  = i / (5 * 68);
                int rem = i - ch * (5 * 68);
                int r   = rem / 68;
                int col = rem - r * 68;
                int y = row + r - 2;
                int x = col - 2;
                float v = 0.f;
                if (y >= 0 && y < WIMG && x >= 0 && x < WIMG)
                    v = qkv[((size_t)b * C3 + cbase + ch) * HW + y * WIMG + x];
                qstage[ch][r][col] = v;
            }
            __syncthreads();
            #pragma unroll
            for (int i = 0; i < 2; i++) {
                int idx = tid + i * 256;
                int ch = idx >> 6, px = idx & 63;   // ch wave-uniform
                int c = cbase + ch;
                const float* wr = &dww[c * 25];
                float s = 0.f;
                #pragma unroll
                for (int ky = 0; ky < 5; ky++)
                    #pragma unroll
                    for (int kx = 0; kx < 5; kx++)
                        s += wr[ky * 5 + kx] * qstage[ch][ky][px + kx];
                float pw = pww[c];
                qbuf[ch][px] = s * pw + (pw * dwb[c] + pwb[c]);
            }
        }
        __syncthreads();

        // attn values for this head: abuf[d][px]
        {
            int px = tid & 63;
            int g  = tid >> 6;        // wave -> d = g, g+4
            float qr[8];
            #pragma unroll
            for (int e = 0; e < 8; e++) qr[e] = fmaxf(qbuf[e][px], 0.f);
            float den = EPS_F;
            #pragma unroll
            for (int e = 0; e < 8; e++) den += sstat[64 + e] * qr[e];
            float rden = 1.f / den;
            #pragma unroll
            for (int dd = 0; dd < 2; dd++) {
                int d = g + dd * 4;
                float num = 0.f;
                #pragma unroll
                for (int e = 0; e < 8; e++) num += sstat[d * 8 + e] * qr[e];
                abuf[d][px] = num * rden;
            }
        }
        __syncthreads();

        // proj accumulation: acc[i][j] += sum_d Wp[c][d] * abuf[d][px]
        float ab[8][4];
        #pragma unroll
        for (int d = 0; d < 8; d++) {
            float4 t = *reinterpret_cast<const float4*>(&abuf[d][tx * 4]);
            ab[d][0] = t.x; ab[d][1] = t.y; ab[d][2] = t.z; ab[d][3] = t.w;
        }
        #pragma unroll
        for (int i = 0; i < 16; i++) {
            int c = ty * 16 + i;
            float4 w0 = *reinterpret_cast<const float4*>(&Wp[c][0]);
            float4 w1 = *reinterpret_cast<const float4*>(&Wp[c][4]);
            float wv[8] = {w0.x, w0.y, w0.z, w0.w, w1.x, w1.y, w1.z, w1.w};
            #pragma unroll
            for (int d = 0; d < 8; d++)
                #pragma unroll
                for (int j = 0; j < 4; j++)
                    acc[i][j] += wv[d] * ab[d][j];
        }
    }

    // epilogue
    #pragma unroll
    for (int i = 0; i < 16; i++) {
        int c = ty * 16 + i;
        float s = scale[c];
        float bi = bias[c];
        float4 v;
        v.x = fmaxf(acc[i][0] * s + bi, 0.f);
        v.y = fmaxf(acc[i][1] * s + bi, 0.f);
        v.z = fmaxf(acc[i][2] * s + bi, 0.f);
        v.w = fmaxf(acc[i][3] * s + bi, 0.f);
        float* dst = out + ((size_t)b * COUT + c) * HW + pt + tx * 4;
        *reinterpret_cast<float4*>(dst) = v;
    }
}

// ---------------------------------------------------------------------------
extern "C" void kernel_launch(void* const* d_in, const int* in_sizes, int n_in,
                              void* d_out, int out_size, void* d_ws, size_t ws_size,
                              hipStream_t stream)
{
    const float* x      = (const float*)d_in[0];
    const float* qkv_w  = (const float*)d_in[1];
    const float* qkv_s  = (const float*)d_in[2];
    const float* qkv_b  = (const float*)d_in[3];
    const float* dw_w   = (const float*)d_in[4];
    const float* dw_b   = (const float*)d_in[5];
    const float* pw_w   = (const float*)d_in[6];
    const float* pw_b   = (const float*)d_in[7];
    const float* proj_w = (const float*)d_in[8];
    const float* proj_s = (const float*)d_in[9];
    const float* proj_b = (const float*)d_in[10];
    float* out = (float*)d_out;

    // workspace: qkv f32 (192 MiB) + stats f32 (288 KiB)  = 192.3 MiB (proven)
    float* qkv   = (float*)d_ws;
    float* stats = qkv + (size_t)BATCH * C3 * HW;

    // 1) qkv = relu(bn(conv1x1(x)))  f32
    conv1x1_bn_relu<CIN><<<dim3(HW / 64, C3 / 64, BATCH), 256, 0, stream>>>(
        x, qkv_w, qkv_s, qkv_b, qkv, C3);

    // 2) stats for heads 0..31 (direct)
    attn_stats_direct<<<dim3(32, BATCH), 256, 0, stream>>>(qkv, stats);

    // 3) stats for heads 32..63 (fused depthwise, agg never materialized)
    attn_stats_dw<<<dim3(32, BATCH), 256, 0, stream>>>(
        qkv, dw_w, dw_b, pw_w, pw_b, stats);

    // 4) fused attention pass-2 + proj + BN + ReLU
    attn_proj<<<dim3(WIMG, BATCH), 256, 0, stream>>>(
        qkv, dw_w, dw_b, pw_w, pw_b, stats, proj_w, proj_s, proj_b, out);
}

// Round 8
// 1299.369 us; speedup vs baseline: 1.2544x; 1.2544x over previous
//
#include <hip/hip_runtime.h>

#define HW    4096
#define WIMG  64
#define CIN   256
#define C3    768
#define COUT  256
#define BATCH 16
#define NHB   32
#define EPS_F 1e-5f
#define QSCALE 1024.0f   // pow2: exactly undone in epilogue

typedef __attribute__((ext_vector_type(8))) short    short8;
typedef __attribute__((ext_vector_type(8))) _Float16 half8;
typedef __attribute__((ext_vector_type(4))) float    floatx4;

__device__ inline short f32_to_bf16(float f) {
    unsigned u = __builtin_bit_cast(unsigned, f);
    unsigned r = u + 0x7fffu + ((u >> 16) & 1u);
    return (short)(r >> 16);
}
__device__ inline float bf16_to_f32(short s) {
    return __builtin_bit_cast(float, ((unsigned)(unsigned short)s) << 16);
}

// ---------------------------------------------------------------------------
// K1a: q channels (packed 256) of qkv 1x1 conv, f32 VALU GEMM.
// q needs f32 absolute accuracy (eps-denominator cliff). Packed channel
// c' in [0,256): real C3 channel = (c'>>3)*24 + (c'&7).
// ---------------------------------------------------------------------------
__global__ __launch_bounds__(256) void conv_q_f32(
    const float* __restrict__ in,     // (B, 256, HW)
    const float* __restrict__ w,      // (768, 256)
    const float* __restrict__ scale,
    const float* __restrict__ bias,
    float* __restrict__ Qf)           // (B, 256, HW) packed q
{
    const int pt  = blockIdx.x * 64;
    const int ct  = blockIdx.y * 64;
    const int b   = blockIdx.z;
    const int tid = threadIdx.x;
    const int tx  = tid & 15;
    const int ty  = tid >> 4;

    __shared__ float Ws[16][64];
    __shared__ float Xs[16][64];

    float acc[4][4] = {};
    const float* xb = in + (size_t)b * CIN * HW + pt;

    for (int k0 = 0; k0 < CIN; k0 += 16) {
        #pragma unroll
        for (int i = 0; i < 4; i++) {
            int idx = tid + i * 256;
            int c = idx >> 4, k = idx & 15;
            int cp = ct + c;
            int creal = (cp >> 3) * 24 + (cp & 7);
            Ws[k][c] = w[(size_t)creal * CIN + k0 + k];
        }
        #pragma unroll
        for (int i = 0; i < 4; i++) {
            int idx = tid + i * 256;
            int k = idx >> 6, p = idx & 63;
            Xs[k][p] = xb[(size_t)(k0 + k) * HW + p];
        }
        __syncthreads();
        #pragma unroll
        for (int kk = 0; kk < 16; kk++) {
            float4 av = *reinterpret_cast<const float4*>(&Ws[kk][ty * 4]);
            float4 bv = *reinterpret_cast<const float4*>(&Xs[kk][tx * 4]);
            float a[4] = {av.x, av.y, av.z, av.w};
            float bb[4] = {bv.x, bv.y, bv.z, bv.w};
            #pragma unroll
            for (int i = 0; i < 4; i++)
                #pragma unroll
                for (int j = 0; j < 4; j++)
                    acc[i][j] += a[i] * bb[j];
        }
        __syncthreads();
    }

    #pragma unroll
    for (int i = 0; i < 4; i++) {
        int cp = ct + ty * 4 + i;
        int creal = (cp >> 3) * 24 + (cp & 7);
        float s = scale[creal];
        float bi = bias[creal];
        float4 v;
        v.x = fmaxf(acc[i][0] * s + bi, 0.f);
        v.y = fmaxf(acc[i][1] * s + bi, 0.f);
        v.z = fmaxf(acc[i][2] * s + bi, 0.f);
        v.w = fmaxf(acc[i][3] * s + bi, 0.f);
        float* dst = Qf + ((size_t)b * 256 + cp) * HW + pt + tx * 4;
        *reinterpret_cast<float4*>(dst) = v;
    }
}

// ---------------------------------------------------------------------------
// K1b: k/v channels (packed 512) via bf16 hi/lo 3-pass MFMA (~f32 accurate).
// Packed c' in [0,512): real = (c'>>4)*24 + 8 + (c'&15). Out f32.
// ---------------------------------------------------------------------------
__global__ __launch_bounds__(256) void conv_kv_mfma(
    const float* __restrict__ x,
    const float* __restrict__ w,
    const float* __restrict__ scale,
    const float* __restrict__ bias,
    float* __restrict__ KV)           // (B, 512, HW) packed k/v, f32
{
    const int ct = blockIdx.x, pt = blockIdx.y, b = blockIdx.z;
    const int tid  = threadIdx.x;
    const int wv   = tid >> 6, lane = tid & 63;
    const int u    = lane & 15, q8 = (lane >> 4) * 8;
    const int chb  = ct * 128 + (wv >> 1) * 64;
    const int pxb  = pt * 128 + (wv & 1) * 64;

    floatx4 acc[4][4];
    #pragma unroll
    for (int i = 0; i < 4; i++)
        #pragma unroll
        for (int j = 0; j < 4; j++) acc[i][j] = (floatx4)0.f;

    for (int kc = 0; kc < 8; kc++) {
        const int k0 = kc * 32 + q8;
        short8 ahi[4], alo[4];
        #pragma unroll
        for (int mt = 0; mt < 4; mt++) {
            int cp = chb + mt * 16 + u;
            int creal = (cp >> 4) * 24 + 8 + (cp & 15);
            const float* wp = w + (size_t)creal * CIN + k0;
            #pragma unroll
            for (int j = 0; j < 8; j++) {
                float f = wp[j];
                short h = f32_to_bf16(f);
                ahi[mt][j] = h;
                alo[mt][j] = f32_to_bf16(f - bf16_to_f32(h));
            }
        }
        short8 bhi[4], blo[4];
        #pragma unroll
        for (int nt = 0; nt < 4; nt++) {
            const float* xp = x + ((size_t)b * CIN + k0) * HW + pxb + nt * 16 + u;
            #pragma unroll
            for (int j = 0; j < 8; j++) {
                float f = xp[(size_t)j * HW];
                short h = f32_to_bf16(f);
                bhi[nt][j] = h;
                blo[nt][j] = f32_to_bf16(f - bf16_to_f32(h));
            }
        }
        #pragma unroll
        for (int mt = 0; mt < 4; mt++)
            #pragma unroll
            for (int nt = 0; nt < 4; nt++) {
                acc[mt][nt] = __builtin_amdgcn_mfma_f32_16x16x32_bf16(ahi[mt], bhi[nt], acc[mt][nt], 0, 0, 0);
                acc[mt][nt] = __builtin_amdgcn_mfma_f32_16x16x32_bf16(ahi[mt], blo[nt], acc[mt][nt], 0, 0, 0);
                acc[mt][nt] = __builtin_amdgcn_mfma_f32_16x16x32_bf16(alo[mt], bhi[nt], acc[mt][nt], 0, 0, 0);
            }
    }

    const int quad = lane >> 4;
    #pragma unroll
    for (int mt = 0; mt < 4; mt++)
        #pragma unroll
        for (int r = 0; r < 4; r++) {
            int cp = chb + mt * 16 + quad * 4 + r;
            int creal = (cp >> 4) * 24 + 8 + (cp & 15);
            float s = scale[creal], bi = bias[creal];
            #pragma unroll
            for (int nt = 0; nt < 4; nt++) {
                int px = pxb + nt * 16 + u;
                KV[((size_t)b * 512 + cp) * HW + px] = fmaxf(acc[mt][nt][r] * s + bi, 0.f);
            }
        }
}

// ---------------------------------------------------------------------------
// K2: stats heads 0..31, direct from KV f32.
// ---------------------------------------------------------------------------
__global__ __launch_bounds__(256) void attn_stats_direct(
    const float* __restrict__ KV,
    float* __restrict__ stats)
{
    const int h = blockIdx.x, b = blockIdx.y;
    const int tid = threadIdx.x;
    const int lane = tid & 63, wave = tid >> 6;

    const float* src = KV + ((size_t)b * 512 + h * 16) * HW;

    float acc[72];
    #pragma unroll
    for (int i = 0; i < 72; i++) acc[i] = 0.f;

    for (int p = tid; p < HW; p += 256) {
        float kv[8], vv[8];
        #pragma unroll
        for (int e = 0; e < 8; e++) kv[e] = fmaxf(src[(size_t)e * HW + p], 0.f);
        #pragma unroll
        for (int d = 0; d < 8; d++) vv[d] = src[(size_t)(8 + d) * HW + p];
        #pragma unroll
        for (int d = 0; d < 8; d++)
            #pragma unroll
            for (int e = 0; e < 8; e++)
                acc[d * 8 + e] += vv[d] * kv[e];
        #pragma unroll
        for (int e = 0; e < 8; e++) acc[64 + e] += kv[e];
    }

    __shared__ float red[4][72];
    #pragma unroll
    for (int i = 0; i < 72; i++) {
        float v = acc[i];
        v += __shfl_down(v, 32); v += __shfl_down(v, 16); v += __shfl_down(v, 8);
        v += __shfl_down(v, 4);  v += __shfl_down(v, 2);  v += __shfl_down(v, 1);
        if (lane == 0) red[wave][i] = v;
    }
    __syncthreads();
    if (tid < 72)
        stats[((size_t)b * 64 + h) * 72 + tid] =
            red[0][tid] + red[1][tid] + red[2][tid] + red[3][tid];
}

// ---------------------------------------------------------------------------
// K3: stats heads 32..63, fused depthwise 5x5 + affine from KV f32.
// ---------------------------------------------------------------------------
__global__ __launch_bounds__(256) void attn_stats_dw(
    const float* __restrict__ KV,
    const float* __restrict__ dww, const float* __restrict__ dwb,
    const float* __restrict__ pww, const float* __restrict__ pwb,
    float* __restrict__ stats)
{
    const int hp = blockIdx.x, b = blockIdx.y;
    const int tid = threadIdx.x;
    const int lane = tid & 63, wave = tid >> 6;
    const int base = hp * 24 + 8;

    __shared__ float stg[16][12][68];
    __shared__ float red[4][72];

    float acc[72];
    #pragma unroll
    for (int i = 0; i < 72; i++) acc[i] = 0.f;

    const int r  = tid >> 5;
    const int x0 = (tid & 31) * 2;

    for (int ys = 0; ys < WIMG; ys += 8) {
        __syncthreads();
        for (int i = tid; i < 16 * 12 * 68; i += 256) {
            int ch  = i / (12 * 68);
            int rem = i - ch * (12 * 68);
            int rr  = rem / 68;
            int col = rem - rr * 68;
            int y = ys + rr - 2, xx = col - 2;
            float v = 0.f;
            if (y >= 0 && y < WIMG && xx >= 0 && xx < WIMG)
                v = KV[((size_t)b * 512 + hp * 16 + ch) * HW + y * WIMG + xx];
            stg[ch][rr][col] = v;
        }
        __syncthreads();

        float kv0[8], vv0[8], kv1[8], vv1[8];
        #pragma unroll
        for (int j = 0; j < 16; j++) {
            int c = base + j;
            const float* wr = &dww[c * 25];
            float s0 = 0.f, s1 = 0.f;
            #pragma unroll
            for (int ky = 0; ky < 5; ky++) {
                float rd[6];
                #pragma unroll
                for (int t = 0; t < 6; t++) rd[t] = stg[j][r + ky][x0 + t];
                #pragma unroll
                for (int kx = 0; kx < 5; kx++) {
                    float wt = wr[ky * 5 + kx];
                    s0 += wt * rd[kx];
                    s1 += wt * rd[kx + 1];
                }
            }
            float pw = pww[c];
            float pb = pw * dwb[c] + pwb[c];
            float v0 = s0 * pw + pb, v1 = s1 * pw + pb;
            if (j < 8) { kv0[j] = fmaxf(v0, 0.f); kv1[j] = fmaxf(v1, 0.f); }
            else       { vv0[j - 8] = v0;         vv1[j - 8] = v1; }
        }
        #pragma unroll
        for (int d = 0; d < 8; d++)
            #pragma unroll
            for (int e = 0; e < 8; e++)
                acc[d * 8 + e] += vv0[d] * kv0[e] + vv1[d] * kv1[e];
        #pragma unroll
        for (int e = 0; e < 8; e++) acc[64 + e] += kv0[e] + kv1[e];
    }

    #pragma unroll
    for (int i = 0; i < 72; i++) {
        float v = acc[i];
        v += __shfl_down(v, 32); v += __shfl_down(v, 16); v += __shfl_down(v, 8);
        v += __shfl_down(v, 4);  v += __shfl_down(v, 2);  v += __shfl_down(v, 1);
        if (lane == 0) red[wave][i] = v;
    }
    __syncthreads();
    if (tid < 72)
        stats[((size_t)b * 64 + 32 + hp) * 72 + tid] =
            red[0][tid] + red[1][tid] + red[2][tid] + red[3][tid];
}

// ---------------------------------------------------------------------------
// K4: fold proj weights with vk, COLUMN-RESCALED by g_e = ksum_e + eps:
// M'[b][c][h*8+e] = (sum_d w[c][h*8+d]*vk[h][d][e]) / g_{h,e}.
// Bounded ~O(w*vbar) regardless of ksum (vk_e/ksum_e is a k-weighted mean
// of v). Dead channels: vk col == 0 exactly -> M' = 0. Stored f16 hi/lo.
// ---------------------------------------------------------------------------
__global__ __launch_bounds__(256) void build_M(
    const float* __restrict__ stats,   // (B,64,72)
    const float* __restrict__ projw,   // (256,512)
    _Float16* __restrict__ Mhi,        // (B,256,512)
    _Float16* __restrict__ Mlo)        // (B,256,512)
{
    const int b = blockIdx.x;
    const int tid = threadIdx.x;
    __shared__ float svk[64][64];
    __shared__ float sginv[64][8];
    for (int i = tid; i < 64 * 64; i += 256)
        svk[i >> 6][i & 63] = stats[((size_t)b * 64 + (i >> 6)) * 72 + (i & 63)];
    for (int i = tid; i < 512; i += 256)
        sginv[i >> 3][i & 7] =
            1.0f / (stats[((size_t)b * 64 + (i >> 3)) * 72 + 64 + (i & 7)] + EPS_F);
    __syncthreads();

    const float* wr = projw + (size_t)tid * 512;
    for (int h = 0; h < 64; h++) {
        float wv[8];
        float4 a0 = *reinterpret_cast<const float4*>(wr + h * 8);
        float4 a1 = *reinterpret_cast<const float4*>(wr + h * 8 + 4);
        wv[0]=a0.x; wv[1]=a0.y; wv[2]=a0.z; wv[3]=a0.w;
        wv[4]=a1.x; wv[5]=a1.y; wv[6]=a1.z; wv[7]=a1.w;
        union { _Float16 h8[8]; uint4 u; } hi, lo;
        #pragma unroll
        for (int e = 0; e < 8; e++) {
            float s = 0.f;
            #pragma unroll
            for (int d = 0; d < 8; d++) s += wv[d] * svk[h][d * 8 + e];
            s *= sginv[h][e];
            _Float16 sh = (_Float16)s;
            hi.h8[e] = sh;
            lo.h8[e] = (_Float16)(s - (float)sh);
        }
        *reinterpret_cast<uint4*>(Mhi + ((size_t)b * 256 + tid) * 512 + h * 8) = hi.u;
        *reinterpret_cast<uint4*>(Mlo + ((size_t)b * 256 + tid) * 512 + h * 8) = lo.u;
    }
}

// ---------------------------------------------------------------------------
// K5: Qt_e = QSCALE * g_e * q_e / den  (g_e = ksum_e + eps) — bounded by
// ~QSCALE*(1+q) by construction, so no clamp truncation (60000 = safety).
// f16 MFMA GEMM out = M' @ Qt, 2-pass hi/lo, epilogue /QSCALE + BN + ReLU.
// ---------------------------------------------------------------------------
__global__ __launch_bounds__(256) void attn_proj_mfma(
    const float* __restrict__ Qf,      // (B,256,HW) packed q
    const float* __restrict__ dww, const float* __restrict__ dwb,
    const float* __restrict__ pww, const float* __restrict__ pwb,
    const float* __restrict__ stats,   // ksum at [64..71]
    const _Float16* __restrict__ Mhi,  // (B,256,512)
    const _Float16* __restrict__ Mlo,
    const float* __restrict__ scale, const float* __restrict__ bias,
    float* __restrict__ out)           // (B,256,HW)
{
    const int row = blockIdx.x, b = blockIdx.y;
    const int pt  = row * 64;
    const int tid = threadIdx.x;
    const int wv  = tid >> 6, lane = tid & 63;

    __shared__ _Float16 Qt[64][264];      // 33.0 KB half-K [px][k]
    __shared__ float    qstage[8][5][68]; // 10.9 KB
    __shared__ float    qbuf[8][64];      // 2 KB
    __shared__ float    ksums[64][8];     // 2 KB

    for (int i = tid; i < 512; i += 256)
        ksums[i >> 3][i & 7] = stats[((size_t)b * 64 + (i >> 3)) * 72 + 64 + (i & 7)];
    __syncthreads();

    const int e0 = wv * 2;
    const int u = lane & 15, q8 = (lane >> 4) * 8;
    const int quad = lane >> 4;

    floatx4 acc[4][4];
    #pragma unroll
    for (int i = 0; i < 4; i++)
        #pragma unroll
        for (int j = 0; j < 4; j++) acc[i][j] = (floatx4)0.f;

    // ================= phase A: heads 0..31 (direct f32 q) =================
    for (int h = 0; h < 32; h++) {
        const int px = lane;
        const float* qp = Qf + ((size_t)b * 256 + h * 8) * HW + pt + px;
        float qv[8];
        #pragma unroll
        for (int e = 0; e < 8; e++) qv[e] = qp[(size_t)e * HW];   // already >= 0
        float den = EPS_F;
        #pragma unroll
        for (int e = 0; e < 8; e++) den += ksums[h][e] * qv[e];
        float rd = QSCALE / den;
        float g0 = ksums[h][e0] + EPS_F, g1 = ksums[h][e0 + 1] + EPS_F;
        Qt[px][h * 8 + e0]     = (_Float16)fminf(qv[e0] * g0 * rd,     60000.f);
        Qt[px][h * 8 + e0 + 1] = (_Float16)fminf(qv[e0 + 1] * g1 * rd, 60000.f);
    }
    __syncthreads();

    // GEMM over K-half 0 (heads 0..31), M hi + lo
    for (int ks = 0; ks < 8; ks++) {
        half8 ah[4], al[4], bf[4];
        #pragma unroll
        for (int mt = 0; mt < 4; mt++) {
            size_t moff = ((size_t)b * 256 + wv * 64 + mt * 16 + u) * 512 + ks * 32 + q8;
            ah[mt] = *reinterpret_cast<const half8*>(Mhi + moff);
            al[mt] = *reinterpret_cast<const half8*>(Mlo + moff);
        }
        #pragma unroll
        for (int nt = 0; nt < 4; nt++)
            bf[nt] = *reinterpret_cast<const half8*>(&Qt[nt * 16 + u][ks * 32 + q8]);
        #pragma unroll
        for (int mt = 0; mt < 4; mt++)
            #pragma unroll
            for (int nt = 0; nt < 4; nt++) {
                acc[mt][nt] = __builtin_amdgcn_mfma_f32_16x16x32_f16(ah[mt], bf[nt], acc[mt][nt], 0, 0, 0);
                acc[mt][nt] = __builtin_amdgcn_mfma_f32_16x16x32_f16(al[mt], bf[nt], acc[mt][nt], 0, 0, 0);
            }
    }

    // ================= phase B: heads 32..63 (f32 dwconv q) ================
    for (int h = 32; h < 64; h++) {
        const int hb = h - 32;
        __syncthreads();   // protects qstage/Qt from previous readers
        for (int i = tid; i < 8 * 5 * 68; i += 256) {
            int ch  = i / 340;
            int rem = i - ch * 340;
            int rr  = rem / 68;
            int col = rem - rr * 68;
            int y = row + rr - 2, xx = col - 2;
            float v = 0.f;
            if (y >= 0 && y < WIMG && xx >= 0 && xx < WIMG)
                v = Qf[((size_t)b * 256 + hb * 8 + ch) * HW + y * WIMG + xx];
            qstage[ch][rr][col] = v;
        }
        __syncthreads();
        {
            int ch = tid >> 5, xg = tid & 31, x0 = xg * 2;
            int c = hb * 24 + ch;
            const float* wr = &dww[c * 25];
            float pw = pww[c];
            float pb = pw * dwb[c] + pwb[c];
            float s0 = 0.f, s1 = 0.f;
            #pragma unroll
            for (int ky = 0; ky < 5; ky++) {
                float rd6[6];
                #pragma unroll
                for (int t = 0; t < 6; t++) rd6[t] = qstage[ch][ky][x0 + t];
                #pragma unroll
                for (int kx = 0; kx < 5; kx++) {
                    float wt = wr[ky * 5 + kx];
                    s0 += wt * rd6[kx];
                    s1 += wt * rd6[kx + 1];
                }
            }
            qbuf[ch][x0]     = s0 * pw + pb;
            qbuf[ch][x0 + 1] = s1 * pw + pb;
        }
        __syncthreads();
        {
            const int px = lane;
            float qv[8];
            #pragma unroll
            for (int e = 0; e < 8; e++) qv[e] = fmaxf(qbuf[e][px], 0.f);
            float den = EPS_F;
            #pragma unroll
            for (int e = 0; e < 8; e++) den += ksums[h][e] * qv[e];
            float rd = QSCALE / den;
            float g0 = ksums[h][e0] + EPS_F, g1 = ksums[h][e0 + 1] + EPS_F;
            Qt[px][hb * 8 + e0]     = (_Float16)fminf(qv[e0] * g0 * rd,     60000.f);
            Qt[px][hb * 8 + e0 + 1] = (_Float16)fminf(qv[e0 + 1] * g1 * rd, 60000.f);
        }
    }
    __syncthreads();

    // GEMM over K-half 1 (heads 32..63)
    for (int ks = 0; ks < 8; ks++) {
        half8 ah[4], al[4], bf[4];
        #pragma unroll
        for (int mt = 0; mt < 4; mt++) {
            size_t moff = ((size_t)b * 256 + wv * 64 + mt * 16 + u) * 512 + 256 + ks * 32 + q8;
            ah[mt] = *reinterpret_cast<const half8*>(Mhi + moff);
            al[mt] = *reinterpret_cast<const half8*>(Mlo + moff);
        }
        #pragma unroll
        for (int nt = 0; nt < 4; nt++)
            bf[nt] = *reinterpret_cast<const half8*>(&Qt[nt * 16 + u][ks * 32 + q8]);
        #pragma unroll
        for (int mt = 0; mt < 4; mt++)
            #pragma unroll
            for (int nt = 0; nt < 4; nt++) {
                acc[mt][nt] = __builtin_amdgcn_mfma_f32_16x16x32_f16(ah[mt], bf[nt], acc[mt][nt], 0, 0, 0);
                acc[mt][nt] = __builtin_amdgcn_mfma_f32_16x16x32_f16(al[mt], bf[nt], acc[mt][nt], 0, 0, 0);
            }
    }

    #pragma unroll
    for (int mt = 0; mt < 4; mt++)
        #pragma unroll
        for (int r = 0; r < 4; r++) {
            int c = wv * 64 + mt * 16 + quad * 4 + r;
            float s = scale[c] * (1.0f / QSCALE);
            float bi = bias[c];
            #pragma unroll
            for (int nt = 0; nt < 4; nt++) {
                int px = pt + nt * 16 + u;
                out[((size_t)b * COUT + c) * HW + px] = fmaxf(acc[mt][nt][r] * s + bi, 0.f);
            }
        }
}

// ---------------------------------------------------------------------------
extern "C" void kernel_launch(void* const* d_in, const int* in_sizes, int n_in,
                              void* d_out, int out_size, void* d_ws, size_t ws_size,
                              hipStream_t stream)
{
    const float* x      = (const float*)d_in[0];
    const float* qkv_w  = (const float*)d_in[1];
    const float* qkv_s  = (const float*)d_in[2];
    const float* qkv_b  = (const float*)d_in[3];
    const float* dw_w   = (const float*)d_in[4];
    const float* dw_b   = (const float*)d_in[5];
    const float* pw_w   = (const float*)d_in[6];
    const float* pw_b   = (const float*)d_in[7];
    const float* proj_w = (const float*)d_in[8];
    const float* proj_s = (const float*)d_in[9];
    const float* proj_b = (const float*)d_in[10];
    float* out = (float*)d_out;

    // ws layout (exactly the PROVEN 192.3 MiB):
    //   [0,128 MiB)    KV f32 (dead after K3; first 8 MiB reused for Mhi/Mlo)
    //   [128,192 MiB)  Qf f32
    //   [192 MiB, +288 KiB) stats
    float*    KV    = (float*)d_ws;
    _Float16* Mhi   = (_Float16*)d_ws;                      // aliases dead KV
    _Float16* Mlo   = Mhi + (size_t)BATCH * 256 * 512;      // +4 MiB
    float*    Qf    = KV + (size_t)BATCH * 512 * HW;
    float*    stats = Qf + (size_t)BATCH * 256 * HW;

    conv_q_f32<<<dim3(HW / 64, 4, BATCH), 256, 0, stream>>>(
        x, qkv_w, qkv_s, qkv_b, Qf);

    conv_kv_mfma<<<dim3(4, 32, BATCH), 256, 0, stream>>>(
        x, qkv_w, qkv_s, qkv_b, KV);

    attn_stats_direct<<<dim3(32, BATCH), 256, 0, stream>>>(KV, stats);

    attn_stats_dw<<<dim3(32, BATCH), 256, 0, stream>>>(
        KV, dw_w, dw_b, pw_w, pw_b, stats);

    build_M<<<dim3(BATCH), 256, 0, stream>>>(stats, proj_w, Mhi, Mlo);

    attn_proj_mfma<<<dim3(WIMG, BATCH), 256, 0, stream>>>(
        Qf, dw_w, dw_b, pw_w, pw_b, stats, Mhi, Mlo, proj_s, proj_b, out);
}

// Round 9
// 1101.208 us; speedup vs baseline: 1.4802x; 1.1799x over previous
//
#include <hip/hip_runtime.h>

#define HW    4096
#define WIMG  64
#define CIN   256
#define C3    768
#define COUT  256
#define BATCH 16
#define NHB   32
#define EPS_F 1e-5f
#define QSCALE 1024.0f   // pow2: exactly undone in epilogue

typedef __attribute__((ext_vector_type(8))) short    short8;
typedef __attribute__((ext_vector_type(8))) _Float16 half8;
typedef __attribute__((ext_vector_type(4))) float    floatx4;

__device__ inline short f32_to_bf16(float f) {
    unsigned u = __builtin_bit_cast(unsigned, f);
    unsigned r = u + 0x7fffu + ((u >> 16) & 1u);
    return (short)(r >> 16);
}
__device__ inline float bf16_to_f32(short s) {
    return __builtin_bit_cast(float, ((unsigned)(unsigned short)s) << 16);
}

// ---------------------------------------------------------------------------
// K1a: q channels (packed 256) of qkv 1x1 conv, f32 VALU GEMM.
// 128x128 tile, 8x8 per thread (split as {t*4, 64+t*4} for 2-way-free LDS).
// q needs f32 absolute accuracy (eps-denominator cliff).
// Packed c' in [0,256): real C3 channel = (c'>>3)*24 + (c'&7).
// ---------------------------------------------------------------------------
__global__ __launch_bounds__(256) void conv_q_f32(
    const float* __restrict__ in,     // (B, 256, HW)
    const float* __restrict__ w,      // (768, 256)
    const float* __restrict__ scale,
    const float* __restrict__ bias,
    float* __restrict__ Qf)           // (B, 256, HW) packed q
{
    const int pt  = blockIdx.x * 128;
    const int ct  = blockIdx.y * 128;
    const int b   = blockIdx.z;
    const int tid = threadIdx.x;
    const int tx  = tid & 15;         // px groups tx*4 and 64+tx*4
    const int ty  = tid >> 4;         // ch groups ty*4 and 64+ty*4

    __shared__ float Ws[16][128];
    __shared__ float Xs[16][128];

    float acc[8][8] = {};
    const float* xb = in + (size_t)b * CIN * HW + pt;

    for (int k0 = 0; k0 < CIN; k0 += 16) {
        #pragma unroll
        for (int i = 0; i < 8; i++) {
            int idx = tid + i * 256;          // 0..2047
            int c = idx >> 4, k = idx & 15;
            int cp = ct + c;
            int creal = (cp >> 3) * 24 + (cp & 7);
            Ws[k][c] = w[(size_t)creal * CIN + k0 + k];
        }
        #pragma unroll
        for (int i = 0; i < 8; i++) {
            int idx = tid + i * 256;
            int k = idx >> 7, p = idx & 127;
            Xs[k][p] = xb[(size_t)(k0 + k) * HW + p];
        }
        __syncthreads();
        #pragma unroll
        for (int kk = 0; kk < 16; kk++) {
            float4 a0 = *reinterpret_cast<const float4*>(&Ws[kk][ty * 4]);
            float4 a1 = *reinterpret_cast<const float4*>(&Ws[kk][64 + ty * 4]);
            float4 b0 = *reinterpret_cast<const float4*>(&Xs[kk][tx * 4]);
            float4 b1 = *reinterpret_cast<const float4*>(&Xs[kk][64 + tx * 4]);
            float a[8] = {a0.x, a0.y, a0.z, a0.w, a1.x, a1.y, a1.z, a1.w};
            float bb[8] = {b0.x, b0.y, b0.z, b0.w, b1.x, b1.y, b1.z, b1.w};
            #pragma unroll
            for (int i = 0; i < 8; i++)
                #pragma unroll
                for (int j = 0; j < 8; j++)
                    acc[i][j] += a[i] * bb[j];
        }
        __syncthreads();
    }

    #pragma unroll
    for (int i = 0; i < 8; i++) {
        int cp = ct + (i < 4 ? ty * 4 + i : 64 + ty * 4 + (i - 4));
        int creal = (cp >> 3) * 24 + (cp & 7);
        float s = scale[creal];
        float bi = bias[creal];
        float4 v0, v1;
        v0.x = fmaxf(acc[i][0] * s + bi, 0.f);
        v0.y = fmaxf(acc[i][1] * s + bi, 0.f);
        v0.z = fmaxf(acc[i][2] * s + bi, 0.f);
        v0.w = fmaxf(acc[i][3] * s + bi, 0.f);
        v1.x = fmaxf(acc[i][4] * s + bi, 0.f);
        v1.y = fmaxf(acc[i][5] * s + bi, 0.f);
        v1.z = fmaxf(acc[i][6] * s + bi, 0.f);
        v1.w = fmaxf(acc[i][7] * s + bi, 0.f);
        float* dst = Qf + ((size_t)b * 256 + cp) * HW + pt;
        *reinterpret_cast<float4*>(dst + tx * 4)      = v0;
        *reinterpret_cast<float4*>(dst + 64 + tx * 4) = v1;
    }
}

// ---------------------------------------------------------------------------
// K1b: k/v channels (packed 512) via bf16 hi/lo 3-pass MFMA (~f32 accurate).
// Packed c' in [0,512): real = (c'>>4)*24 + 8 + (c'&15). Out f32.
// ---------------------------------------------------------------------------
__global__ __launch_bounds__(256) void conv_kv_mfma(
    const float* __restrict__ x,
    const float* __restrict__ w,
    const float* __restrict__ scale,
    const float* __restrict__ bias,
    float* __restrict__ KV)           // (B, 512, HW) packed k/v, f32
{
    const int ct = blockIdx.x, pt = blockIdx.y, b = blockIdx.z;
    const int tid  = threadIdx.x;
    const int wv   = tid >> 6, lane = tid & 63;
    const int u    = lane & 15, q8 = (lane >> 4) * 8;
    const int chb  = ct * 128 + (wv >> 1) * 64;
    const int pxb  = pt * 128 + (wv & 1) * 64;

    floatx4 acc[4][4];
    #pragma unroll
    for (int i = 0; i < 4; i++)
        #pragma unroll
        for (int j = 0; j < 4; j++) acc[i][j] = (floatx4)0.f;

    for (int kc = 0; kc < 8; kc++) {
        const int k0 = kc * 32 + q8;
        short8 ahi[4], alo[4];
        #pragma unroll
        for (int mt = 0; mt < 4; mt++) {
            int cp = chb + mt * 16 + u;
            int creal = (cp >> 4) * 24 + 8 + (cp & 15);
            const float* wp = w + (size_t)creal * CIN + k0;
            #pragma unroll
            for (int j = 0; j < 8; j++) {
                float f = wp[j];
                short h = f32_to_bf16(f);
                ahi[mt][j] = h;
                alo[mt][j] = f32_to_bf16(f - bf16_to_f32(h));
            }
        }
        short8 bhi[4], blo[4];
        #pragma unroll
        for (int nt = 0; nt < 4; nt++) {
            const float* xp = x + ((size_t)b * CIN + k0) * HW + pxb + nt * 16 + u;
            #pragma unroll
            for (int j = 0; j < 8; j++) {
                float f = xp[(size_t)j * HW];
                short h = f32_to_bf16(f);
                bhi[nt][j] = h;
                blo[nt][j] = f32_to_bf16(f - bf16_to_f32(h));
            }
        }
        #pragma unroll
        for (int mt = 0; mt < 4; mt++)
            #pragma unroll
            for (int nt = 0; nt < 4; nt++) {
                acc[mt][nt] = __builtin_amdgcn_mfma_f32_16x16x32_bf16(ahi[mt], bhi[nt], acc[mt][nt], 0, 0, 0);
                acc[mt][nt] = __builtin_amdgcn_mfma_f32_16x16x32_bf16(ahi[mt], blo[nt], acc[mt][nt], 0, 0, 0);
                acc[mt][nt] = __builtin_amdgcn_mfma_f32_16x16x32_bf16(alo[mt], bhi[nt], acc[mt][nt], 0, 0, 0);
            }
    }

    const int quad = lane >> 4;
    #pragma unroll
    for (int mt = 0; mt < 4; mt++)
        #pragma unroll
        for (int r = 0; r < 4; r++) {
            int cp = chb + mt * 16 + quad * 4 + r;
            int creal = (cp >> 4) * 24 + 8 + (cp & 15);
            float s = scale[creal], bi = bias[creal];
            #pragma unroll
            for (int nt = 0; nt < 4; nt++) {
                int px = pxb + nt * 16 + u;
                KV[((size_t)b * 512 + cp) * HW + px] = fmaxf(acc[mt][nt][r] * s + bi, 0.f);
            }
        }
}

// ---------------------------------------------------------------------------
// K2: stats heads 0..31, direct from KV f32.
// ---------------------------------------------------------------------------
__global__ __launch_bounds__(256) void attn_stats_direct(
    const float* __restrict__ KV,
    float* __restrict__ stats)
{
    const int h = blockIdx.x, b = blockIdx.y;
    const int tid = threadIdx.x;
    const int lane = tid & 63, wave = tid >> 6;

    const float* src = KV + ((size_t)b * 512 + h * 16) * HW;

    float acc[72];
    #pragma unroll
    for (int i = 0; i < 72; i++) acc[i] = 0.f;

    for (int p = tid; p < HW; p += 256) {
        float kv[8], vv[8];
        #pragma unroll
        for (int e = 0; e < 8; e++) kv[e] = fmaxf(src[(size_t)e * HW + p], 0.f);
        #pragma unroll
        for (int d = 0; d < 8; d++) vv[d] = src[(size_t)(8 + d) * HW + p];
        #pragma unroll
        for (int d = 0; d < 8; d++)
            #pragma unroll
            for (int e = 0; e < 8; e++)
                acc[d * 8 + e] += vv[d] * kv[e];
        #pragma unroll
        for (int e = 0; e < 8; e++) acc[64 + e] += kv[e];
    }

    __shared__ float red[4][72];
    #pragma unroll
    for (int i = 0; i < 72; i++) {
        float v = acc[i];
        v += __shfl_down(v, 32); v += __shfl_down(v, 16); v += __shfl_down(v, 8);
        v += __shfl_down(v, 4);  v += __shfl_down(v, 2);  v += __shfl_down(v, 1);
        if (lane == 0) red[wave][i] = v;
    }
    __syncthreads();
    if (tid < 72)
        stats[((size_t)b * 64 + h) * 72 + tid] =
            red[0][tid] + red[1][tid] + red[2][tid] + red[3][tid];
}

// ---------------------------------------------------------------------------
// K3: stats heads 32..63, fused depthwise 5x5 + affine from KV f32.
// ---------------------------------------------------------------------------
__global__ __launch_bounds__(256) void attn_stats_dw(
    const float* __restrict__ KV,
    const float* __restrict__ dww, const float* __restrict__ dwb,
    const float* __restrict__ pww, const float* __restrict__ pwb,
    float* __restrict__ stats)
{
    const int hp = blockIdx.x, b = blockIdx.y;
    const int tid = threadIdx.x;
    const int lane = tid & 63, wave = tid >> 6;
    const int base = hp * 24 + 8;

    __shared__ float stg[16][12][68];
    __shared__ float red[4][72];

    float acc[72];
    #pragma unroll
    for (int i = 0; i < 72; i++) acc[i] = 0.f;

    const int r  = tid >> 5;
    const int x0 = (tid & 31) * 2;

    for (int ys = 0; ys < WIMG; ys += 8) {
        __syncthreads();
        for (int i = tid; i < 16 * 12 * 68; i += 256) {
            int ch  = i / (12 * 68);
            int rem = i - ch * (12 * 68);
            int rr  = rem / 68;
            int col = rem - rr * 68;
            int y = ys + rr - 2, xx = col - 2;
            float v = 0.f;
            if (y >= 0 && y < WIMG && xx >= 0 && xx < WIMG)
                v = KV[((size_t)b * 512 + hp * 16 + ch) * HW + y * WIMG + xx];
            stg[ch][rr][col] = v;
        }
        __syncthreads();

        float kv0[8], vv0[8], kv1[8], vv1[8];
        #pragma unroll
        for (int j = 0; j < 16; j++) {
            int c = base + j;
            const float* wr = &dww[c * 25];
            float s0 = 0.f, s1 = 0.f;
            #pragma unroll
            for (int ky = 0; ky < 5; ky++) {
                float rd[6];
                #pragma unroll
                for (int t = 0; t < 6; t++) rd[t] = stg[j][r + ky][x0 + t];
                #pragma unroll
                for (int kx = 0; kx < 5; kx++) {
                    float wt = wr[ky * 5 + kx];
                    s0 += wt * rd[kx];
                    s1 += wt * rd[kx + 1];
                }
            }
            float pw = pww[c];
            float pb = pw * dwb[c] + pwb[c];
            float v0 = s0 * pw + pb, v1 = s1 * pw + pb;
            if (j < 8) { kv0[j] = fmaxf(v0, 0.f); kv1[j] = fmaxf(v1, 0.f); }
            else       { vv0[j - 8] = v0;         vv1[j - 8] = v1; }
        }
        #pragma unroll
        for (int d = 0; d < 8; d++)
            #pragma unroll
            for (int e = 0; e < 8; e++)
                acc[d * 8 + e] += vv0[d] * kv0[e] + vv1[d] * kv1[e];
        #pragma unroll
        for (int e = 0; e < 8; e++) acc[64 + e] += kv0[e] + kv1[e];
    }

    #pragma unroll
    for (int i = 0; i < 72; i++) {
        float v = acc[i];
        v += __shfl_down(v, 32); v += __shfl_down(v, 16); v += __shfl_down(v, 8);
        v += __shfl_down(v, 4);  v += __shfl_down(v, 2);  v += __shfl_down(v, 1);
        if (lane == 0) red[wave][i] = v;
    }
    __syncthreads();
    if (tid < 72)
        stats[((size_t)b * 64 + 32 + hp) * 72 + tid] =
            red[0][tid] + red[1][tid] + red[2][tid] + red[3][tid];
}

// ---------------------------------------------------------------------------
// K3b: Qagg = depthwise 5x5 + affine of q channels (f32), materialized into
// dead-KV workspace. Removes the per-head serialization from K5.
// Block per (head-block, batch); 8-row strips. Raw output (relu in K5).
// ---------------------------------------------------------------------------
__global__ __launch_bounds__(256) void q_dwconv(
    const float* __restrict__ Qf,     // (B,256,HW) packed q
    const float* __restrict__ dww, const float* __restrict__ dwb,
    const float* __restrict__ pww, const float* __restrict__ pwb,
    float* __restrict__ Qagg)         // (B,256,HW) packed dwconv(q)
{
    const int hb = blockIdx.x, b = blockIdx.y;
    const int tid = threadIdx.x;

    __shared__ float stg[8][12][68];  // 26.1 KB

    const int r  = tid >> 5;          // 0..7 output row in strip
    const int x0 = (tid & 31) * 2;    // 2 px per thread

    for (int ys = 0; ys < WIMG; ys += 8) {
        __syncthreads();
        for (int i = tid; i < 8 * 12 * 68; i += 256) {
            int ch  = i / (12 * 68);
            int rem = i - ch * (12 * 68);
            int rr  = rem / 68;
            int col = rem - rr * 68;
            int y = ys + rr - 2, xx = col - 2;
            float v = 0.f;
            if (y >= 0 && y < WIMG && xx >= 0 && xx < WIMG)
                v = Qf[((size_t)b * 256 + hb * 8 + ch) * HW + y * WIMG + xx];
            stg[ch][rr][col] = v;
        }
        __syncthreads();

        #pragma unroll
        for (int ch = 0; ch < 8; ch++) {
            int c = hb * 24 + ch;               // real C3 channel (q of agg)
            const float* wr = &dww[c * 25];
            float pw = pww[c];
            float pb = pw * dwb[c] + pwb[c];
            float s0 = 0.f, s1 = 0.f;
            #pragma unroll
            for (int ky = 0; ky < 5; ky++) {
                float rd[6];
                #pragma unroll
                for (int t = 0; t < 6; t++) rd[t] = stg[ch][r + ky][x0 + t];
                #pragma unroll
                for (int kx = 0; kx < 5; kx++) {
                    float wt = wr[ky * 5 + kx];
                    s0 += wt * rd[kx];
                    s1 += wt * rd[kx + 1];
                }
            }
            float2 o = {s0 * pw + pb, s1 * pw + pb};
            float* dst = Qagg + ((size_t)b * 256 + hb * 8 + ch) * HW + (ys + r) * WIMG + x0;
            *reinterpret_cast<float2*>(dst) = o;
        }
    }
}

// ---------------------------------------------------------------------------
// K4: fold proj weights with vk, COLUMN-RESCALED by g_e = ksum_e + eps:
// M'[b][c][h*8+e] = (sum_d w[c][h*8+d]*vk[h][d][e]) / g_{h,e}. f16 hi/lo.
// ---------------------------------------------------------------------------
__global__ __launch_bounds__(256) void build_M(
    const float* __restrict__ stats,   // (B,64,72)
    const float* __restrict__ projw,   // (256,512)
    _Float16* __restrict__ Mhi,        // (B,256,512)
    _Float16* __restrict__ Mlo)
{
    const int b = blockIdx.x;
    const int tid = threadIdx.x;
    __shared__ float svk[64][64];
    __shared__ float sginv[64][8];
    for (int i = tid; i < 64 * 64; i += 256)
        svk[i >> 6][i & 63] = stats[((size_t)b * 64 + (i >> 6)) * 72 + (i & 63)];
    for (int i = tid; i < 512; i += 256)
        sginv[i >> 3][i & 7] =
            1.0f / (stats[((size_t)b * 64 + (i >> 3)) * 72 + 64 + (i & 7)] + EPS_F);
    __syncthreads();

    const float* wr = projw + (size_t)tid * 512;
    for (int h = 0; h < 64; h++) {
        float wv[8];
        float4 a0 = *reinterpret_cast<const float4*>(wr + h * 8);
        float4 a1 = *reinterpret_cast<const float4*>(wr + h * 8 + 4);
        wv[0]=a0.x; wv[1]=a0.y; wv[2]=a0.z; wv[3]=a0.w;
        wv[4]=a1.x; wv[5]=a1.y; wv[6]=a1.z; wv[7]=a1.w;
        union { _Float16 h8[8]; uint4 u; } hi, lo;
        #pragma unroll
        for (int e = 0; e < 8; e++) {
            float s = 0.f;
            #pragma unroll
            for (int d = 0; d < 8; d++) s += wv[d] * svk[h][d * 8 + e];
            s *= sginv[h][e];
            _Float16 sh = (_Float16)s;
            hi.h8[e] = sh;
            lo.h8[e] = (_Float16)(s - (float)sh);
        }
        *reinterpret_cast<uint4*>(Mhi + ((size_t)b * 256 + tid) * 512 + h * 8) = hi.u;
        *reinterpret_cast<uint4*>(Mlo + ((size_t)b * 256 + tid) * 512 + h * 8) = lo.u;
    }
}

// ---------------------------------------------------------------------------
// K5: 128-px tile, 4 barriers total. Qt_e = QSCALE*g_e*q_e/den (bounded),
// f16; two half-K phases (heads 0..31 from Qf, 32..63 from Qagg), each a
// 2-pass hi/lo f16 MFMA GEMM (256ch x 128px). LDS ~70 KB -> 2 blocks/CU.
// ---------------------------------------------------------------------------
__global__ __launch_bounds__(256) void attn_proj_mfma(
    const float* __restrict__ Qf,      // (B,256,HW) packed q (>=0)
    const float* __restrict__ Qagg,    // (B,256,HW) packed dwconv(q), raw
    const float* __restrict__ stats,   // ksum at [64..71]
    const _Float16* __restrict__ Mhi,  // (B,256,512)
    const _Float16* __restrict__ Mlo,
    const float* __restrict__ scale, const float* __restrict__ bias,
    float* __restrict__ out)           // (B,256,HW)
{
    const int pt  = blockIdx.x * 128;
    const int b   = blockIdx.y;
    const int tid = threadIdx.x;
    const int wv  = tid >> 6, lane = tid & 63;

    __shared__ _Float16 Qt[128][264];     // 67.6 KB half-K [px][k]
    __shared__ float    ksums[64][8];     // 2 KB

    for (int i = tid; i < 512; i += 256)
        ksums[i >> 3][i & 7] = stats[((size_t)b * 64 + (i >> 3)) * 72 + 64 + (i & 7)];
    __syncthreads();

    const int pxl = tid & 127;            // local pixel for Qt build
    const int eg  = (tid >> 7) * 4;       // 4 e's per thread
    const int u = lane & 15, q8 = (lane >> 4) * 8;
    const int quad = lane >> 4;

    floatx4 acc[4][8];
    #pragma unroll
    for (int i = 0; i < 4; i++)
        #pragma unroll
        for (int j = 0; j < 8; j++) acc[i][j] = (floatx4)0.f;

    // ============ phase A: heads 0..31 (q direct from Qf, >=0) ============
    for (int h = 0; h < 32; h++) {
        const float* qp = Qf + ((size_t)b * 256 + h * 8) * HW + pt + pxl;
        float qv[8];
        #pragma unroll
        for (int e = 0; e < 8; e++) qv[e] = qp[(size_t)e * HW];
        float den = EPS_F;
        #pragma unroll
        for (int e = 0; e < 8; e++) den += ksums[h][e] * qv[e];
        float rd = QSCALE / den;
        union { _Float16 h4[4]; uint2 u2; } pk;
        #pragma unroll
        for (int j = 0; j < 4; j++) {
            float g = ksums[h][eg + j] + EPS_F;
            pk.h4[j] = (_Float16)fminf(qv[eg + j] * g * rd, 60000.f);
        }
        *reinterpret_cast<uint2*>(&Qt[pxl][h * 8 + eg]) = pk.u2;
    }
    __syncthreads();

    for (int ks = 0; ks < 8; ks++) {
        half8 ah[4], al[4], bf[8];
        #pragma unroll
        for (int mt = 0; mt < 4; mt++) {
            size_t moff = ((size_t)b * 256 + wv * 64 + mt * 16 + u) * 512 + ks * 32 + q8;
            ah[mt] = *reinterpret_cast<const half8*>(Mhi + moff);
            al[mt] = *reinterpret_cast<const half8*>(Mlo + moff);
        }
        #pragma unroll
        for (int nt = 0; nt < 8; nt++)
            bf[nt] = *reinterpret_cast<const half8*>(&Qt[nt * 16 + u][ks * 32 + q8]);
        #pragma unroll
        for (int mt = 0; mt < 4; mt++)
            #pragma unroll
            for (int nt = 0; nt < 8; nt++) {
                acc[mt][nt] = __builtin_amdgcn_mfma_f32_16x16x32_f16(ah[mt], bf[nt], acc[mt][nt], 0, 0, 0);
                acc[mt][nt] = __builtin_amdgcn_mfma_f32_16x16x32_f16(al[mt], bf[nt], acc[mt][nt], 0, 0, 0);
            }
    }
    __syncthreads();

    // ============ phase B: heads 32..63 (q from Qagg, needs relu) ==========
    for (int h = 32; h < 64; h++) {
        const int hb = h - 32;
        const float* qp = Qagg + ((size_t)b * 256 + hb * 8) * HW + pt + pxl;
        float qv[8];
        #pragma unroll
        for (int e = 0; e < 8; e++) qv[e] = fmaxf(qp[(size_t)e * HW], 0.f);
        float den = EPS_F;
        #pragma unroll
        for (int e = 0; e < 8; e++) den += ksums[h][e] * qv[e];
        float rd = QSCALE / den;
        union { _Float16 h4[4]; uint2 u2; } pk;
        #pragma unroll
        for (int j = 0; j < 4; j++) {
            float g = ksums[h][eg + j] + EPS_F;
            pk.h4[j] = (_Float16)fminf(qv[eg + j] * g * rd, 60000.f);
        }
        *reinterpret_cast<uint2*>(&Qt[pxl][hb * 8 + eg]) = pk.u2;
    }
    __syncthreads();

    for (int ks = 0; ks < 8; ks++) {
        half8 ah[4], al[4], bf[8];
        #pragma unroll
        for (int mt = 0; mt < 4; mt++) {
            size_t moff = ((size_t)b * 256 + wv * 64 + mt * 16 + u) * 512 + 256 + ks * 32 + q8;
            ah[mt] = *reinterpret_cast<const half8*>(Mhi + moff);
            al[mt] = *reinterpret_cast<const half8*>(Mlo + moff);
        }
        #pragma unroll
        for (int nt = 0; nt < 8; nt++)
            bf[nt] = *reinterpret_cast<const half8*>(&Qt[nt * 16 + u][ks * 32 + q8]);
        #pragma unroll
        for (int mt = 0; mt < 4; mt++)
            #pragma unroll
            for (int nt = 0; nt < 8; nt++) {
                acc[mt][nt] = __builtin_amdgcn_mfma_f32_16x16x32_f16(ah[mt], bf[nt], acc[mt][nt], 0, 0, 0);
                acc[mt][nt] = __builtin_amdgcn_mfma_f32_16x16x32_f16(al[mt], bf[nt], acc[mt][nt], 0, 0, 0);
            }
    }

    #pragma unroll
    for (int mt = 0; mt < 4; mt++)
        #pragma unroll
        for (int r = 0; r < 4; r++) {
            int c = wv * 64 + mt * 16 + quad * 4 + r;
            float s = scale[c] * (1.0f / QSCALE);
            float bi = bias[c];
            #pragma unroll
            for (int nt = 0; nt < 8; nt++) {
                int px = pt + nt * 16 + u;
                out[((size_t)b * COUT + c) * HW + px] = fmaxf(acc[mt][nt][r] * s + bi, 0.f);
            }
        }
}

// ---------------------------------------------------------------------------
extern "C" void kernel_launch(void* const* d_in, const int* in_sizes, int n_in,
                              void* d_out, int out_size, void* d_ws, size_t ws_size,
                              hipStream_t stream)
{
    const float* x      = (const float*)d_in[0];
    const float* qkv_w  = (const float*)d_in[1];
    const float* qkv_s  = (const float*)d_in[2];
    const float* qkv_b  = (const float*)d_in[3];
    const float* dw_w   = (const float*)d_in[4];
    const float* dw_b   = (const float*)d_in[5];
    const float* pw_w   = (const float*)d_in[6];
    const float* pw_b   = (const float*)d_in[7];
    const float* proj_w = (const float*)d_in[8];
    const float* proj_s = (const float*)d_in[9];
    const float* proj_b = (const float*)d_in[10];
    float* out = (float*)d_out;

    // ws layout (exactly the PROVEN 192.3 MiB):
    //   [0,128 MiB)    KV f32 — dead after K2/K3; reused: Mhi(4)+Mlo(4)+Qagg(64)
    //   [128,192 MiB)  Qf f32
    //   [192 MiB,+288K) stats
    float*    KV    = (float*)d_ws;
    _Float16* Mhi   = (_Float16*)d_ws;                          // +0
    _Float16* Mlo   = Mhi + (size_t)BATCH * 256 * 512;          // +4 MiB
    float*    Qagg  = (float*)(Mlo + (size_t)BATCH * 256 * 512);// +8 MiB (64 MiB)
    float*    Qf    = KV + (size_t)BATCH * 512 * HW;            // +128 MiB
    float*    stats = Qf + (size_t)BATCH * 256 * HW;            // +192 MiB

    conv_q_f32<<<dim3(HW / 128, 2, BATCH), 256, 0, stream>>>(
        x, qkv_w, qkv_s, qkv_b, Qf);

    conv_kv_mfma<<<dim3(4, 32, BATCH), 256, 0, stream>>>(
        x, qkv_w, qkv_s, qkv_b, KV);

    attn_stats_direct<<<dim3(32, BATCH), 256, 0, stream>>>(KV, stats);

    attn_stats_dw<<<dim3(32, BATCH), 256, 0, stream>>>(
        KV, dw_w, dw_b, pw_w, pw_b, stats);

    // after K2/K3: KV region dead -> safe to overwrite with Qagg / M
    q_dwconv<<<dim3(32, BATCH), 256, 0, stream>>>(
        Qf, dw_w, dw_b, pw_w, pw_b, Qagg);

    build_M<<<dim3(BATCH), 256, 0, stream>>>(stats, proj_w, Mhi, Mlo);

    attn_proj_mfma<<<dim3(HW / 128, BATCH), 256, 0, stream>>>(
        Qf, Qagg, stats, Mhi, Mlo, proj_s, proj_b, out);
}